// Round 5
// baseline (44.855 us; speedup 1.0000x reference)
//
#include <hip/hip_runtime.h>
#include <hip/hip_bf16.h>

#define NB 16
#define NN 256
#define NH 8
#define ND 64
#define NT 5

typedef __bf16 bf16x8 __attribute__((ext_vector_type(8)));
typedef float  f32x4  __attribute__((ext_vector_type(4)));

__device__ __forceinline__ bf16x8 cvt8(float4 a, float4 b) {
    bf16x8 r;
    r[0] = (__bf16)a.x; r[1] = (__bf16)a.y; r[2] = (__bf16)a.z; r[3] = (__bf16)a.w;
    r[4] = (__bf16)b.x; r[5] = (__bf16)b.y; r[6] = (__bf16)b.z; r[7] = (__bf16)b.w;
    return r;
}

// Transpose a[(h*64+dd)*64*5 + e*5 + t] (fp32) -> wt[h][t][e][dd] (bf16).
__global__ void prep_w_kernel(const float* __restrict__ a, __bf16* __restrict__ wt) {
    int idx = blockIdx.x * 256 + threadIdx.x;
    if (idx >= NH * ND * ND * NT) return;
    int t  = idx % NT;
    int e  = (idx / NT) % ND;
    int dd = (idx / (NT * ND)) % ND;
    int h  = idx / (NT * ND * ND);
    wt[(((h * NT + t) * ND + e) * ND) + dd] = (__bf16)a[idx];
}

template <bool USE_WT>
__global__ __launch_bounds__(256, 4) void mhea_kernel(
    const float* __restrict__ src, const float* __restrict__ dst,
    const float* __restrict__ araw, const __bf16* __restrict__ wt,
    const int* __restrict__ edges, float* __restrict__ out)
{
    // P_t staging: [t][i(16)][e(64)] bf16, swizzled: elem-index ^ ((i&7)<<3)
    __shared__ __bf16 Plds[NT * 16 * 64];   // 10 KB

    const int it = blockIdx.x;   // 16-row i tile (16 tiles)
    const int h  = blockIdx.y;
    const int b  = blockIdx.z;
    const int i0 = it * 16;

    const int tid = threadIdx.x;
    const int w   = tid >> 6;    // wave 0..3: phase-1 e-tile, phase-2 j-quarter
    const int l   = tid & 63;
    const int il  = l & 15;
    const int kg  = l >> 4;      // lane k-group 0..3

    // ---------- entry prefetch: j-tiles 0,1 of this wave's quarter ----------
    const int jbase = w * 64;
    const float* dbase = dst + (size_t)b * NN * (NH * ND) + h * ND;
    const int*   erow  = edges + ((size_t)b * NN + i0 + il) * NN;

    const float* dpA = dbase + (size_t)(jbase + 0 * 16 + il) * (NH * ND) + kg * 8;
    const float* dpB = dbase + (size_t)(jbase + 1 * 16 + il) * (NH * ND) + kg * 8;
    float4 ra0 = *reinterpret_cast<const float4*>(dpA);
    float4 ra1 = *reinterpret_cast<const float4*>(dpA + 4);
    float4 rb0 = *reinterpret_cast<const float4*>(dpB);
    float4 rb1 = *reinterpret_cast<const float4*>(dpB + 4);
    int4 ea = *reinterpret_cast<const int4*>(erow + jbase + 0 * 16 + kg * 4);
    int4 eb = *reinterpret_cast<const int4*>(erow + jbase + 1 * 16 + kg * 4);

    // ---------- Phase 1: P_t[i,e] = sum_dd s[i,dd] * W_t[dd,e] (e-tile = w) ----------
    const float* sbase = src + (size_t)(b * NN + i0 + il) * (NH * ND) + h * ND;
    {
        float4 s0 = *reinterpret_cast<const float4*>(sbase + kg * 8);
        float4 s1 = *reinterpret_cast<const float4*>(sbase + kg * 8 + 4);
        float4 s2 = *reinterpret_cast<const float4*>(sbase + 32 + kg * 8);
        float4 s3 = *reinterpret_cast<const float4*>(sbase + 32 + kg * 8 + 4);
        bf16x8 af0 = cvt8(s0, s1);
        bf16x8 af1 = cvt8(s2, s3);

        const int e = w * 16 + il;
        #pragma unroll
        for (int t = 0; t < NT; ++t) {
            bf16x8 b0, b1;
            if constexpr (USE_WT) {
                const __bf16* wp = wt + (((h * NT + t) * ND + e) * ND) + kg * 8;
                b0 = *reinterpret_cast<const bf16x8*>(wp);
                b1 = *reinterpret_cast<const bf16x8*>(wp + 32);
            } else {
                #pragma unroll
                for (int jj = 0; jj < 8; ++jj) {
                    const int d0 = kg * 8 + jj;
                    b0[jj] = (__bf16)araw[((size_t)(h * ND + d0) * ND + e) * NT + t];
                    b1[jj] = (__bf16)araw[((size_t)(h * ND + d0 + 32) * ND + e) * NT + t];
                }
            }
            f32x4 acc = {0.f, 0.f, 0.f, 0.f};
            acc = __builtin_amdgcn_mfma_f32_16x16x32_bf16(af0, b0, acc, 0, 0, 0);
            acc = __builtin_amdgcn_mfma_f32_16x16x32_bf16(af1, b1, acc, 0, 0, 0);
            // C layout: col(e)=lane&15, row(i)=(lane>>4)*4+r  [m89/m91]
            #pragma unroll
            for (int r = 0; r < 4; ++r) {
                const int ip = kg * 4 + r;
                Plds[t * 1024 + ip * 64 + (e ^ ((ip & 7) << 3))] = (__bf16)acc[r];
            }
        }
    }

    __syncthreads();

    // ---------- Phase 2: A=dst(j rows), B=P(i) -> lane holds 4 consecutive j ----------
    bf16x8 pa[NT][2];
    #pragma unroll
    for (int t = 0; t < NT; ++t) {
        #pragma unroll
        for (int ks = 0; ks < 2; ++ks) {
            const int k = ks * 32 + kg * 8;
            pa[t][ks] = *reinterpret_cast<const bf16x8*>(
                &Plds[t * 1024 + il * 64 + (k ^ ((il & 7) << 3))]);
        }
    }

    float* obase = out + (((size_t)(b * NH + h)) * NN + i0 + il) * NN;

    #define DO_JT(JT, R0, R1, EV, RELOAD_JT)                                          \
    {                                                                                 \
        const bf16x8 cb0 = cvt8(R0, R1);                                              \
        float4 t0 = R0, t1 = R1; /* keep second half */                               \
        (void)t0; (void)t1;                                                           \
        const float* dpc = dbase + (size_t)(jbase + (JT) * 16 + il) * (NH * ND) + kg * 8; \
        const bf16x8 cb1 = cvt8(*reinterpret_cast<const float4*>(dpc + 32),           \
                                *reinterpret_cast<const float4*>(dpc + 36));          \
        const int4 ce = EV;                                                           \
        if ((RELOAD_JT) < 4) {                                                        \
            const float* dpn = dbase + (size_t)(jbase + (RELOAD_JT) * 16 + il) * (NH * ND) + kg * 8; \
            R0 = *reinterpret_cast<const float4*>(dpn);                               \
            R1 = *reinterpret_cast<const float4*>(dpn + 4);                           \
            EV = *reinterpret_cast<const int4*>(erow + jbase + (RELOAD_JT) * 16 + kg * 4); \
        }                                                                             \
        f32x4 acc[NT];                                                                \
        _Pragma("unroll")                                                             \
        for (int t = 0; t < NT; ++t) {                                                \
            acc[t] = (f32x4){0.f, 0.f, 0.f, 0.f};                                     \
            acc[t] = __builtin_amdgcn_mfma_f32_16x16x32_bf16(cb0, pa[t][0], acc[t], 0, 0, 0); \
            acc[t] = __builtin_amdgcn_mfma_f32_16x16x32_bf16(cb1, pa[t][1], acc[t], 0, 0, 0); \
        }                                                                             \
        float4 o;                                                                     \
        _Pragma("unroll")                                                             \
        for (int r = 0; r < 4; ++r) {                                                 \
            const int ev = (&ce.x)[r];                                                \
            float x;                                                                  \
            if (ev < 0) { x = -1e10f; }                                               \
            else {                                                                    \
                x = (ev == 0) ? acc[0][r]                                             \
                  : (ev == 1) ? acc[1][r]                                             \
                  : (ev == 2) ? acc[2][r]                                             \
                  : (ev == 3) ? acc[3][r]                                             \
                  :             acc[4][r];                                            \
            }                                                                         \
            (&o.x)[r] = (x >= 0.f) ? x : 0.2f * x;                                    \
        }                                                                             \
        *reinterpret_cast<float4*>(obase + jbase + (JT) * 16 + kg * 4) = o;           \
    }

    // NOTE: entry prefetch only covered the FIRST 32B of each dst row (ra0/ra1 =
    // first bf16x8 fragment); the second fragment (cols 32..63) is loaded inside
    // DO_JT (dpc+32). Depth-2 rotation: A,B buffers alternate; jt+2 reloads.
    DO_JT(0, ra0, ra1, ea, 2)
    DO_JT(1, rb0, rb1, eb, 3)
    DO_JT(2, ra0, ra1, ea, 4)
    DO_JT(3, rb0, rb1, eb, 4)

    #undef DO_JT
}

extern "C" void kernel_launch(void* const* d_in, const int* in_sizes, int n_in,
                              void* d_out, int out_size, void* d_ws, size_t ws_size,
                              hipStream_t stream) {
    const float* src   = (const float*)d_in[0];
    const float* dst   = (const float*)d_in[1];
    const float* a     = (const float*)d_in[2];
    const int*   edges = (const int*)d_in[3];
    float* out = (float*)d_out;

    const size_t wt_bytes = (size_t)NH * NT * ND * ND * sizeof(__bf16);
    dim3 grid(NN / 16, NH, NB);

    if (ws_size >= wt_bytes) {
        __bf16* wt = (__bf16*)d_ws;
        const int total = NH * ND * ND * NT;
        prep_w_kernel<<<(total + 255) / 256, 256, 0, stream>>>(a, wt);
        mhea_kernel<true><<<grid, 256, 0, stream>>>(src, dst, a, wt, edges, out);
    } else {
        mhea_kernel<false><<<grid, 256, 0, stream>>>(src, dst, a, nullptr, edges, out);
    }
}

// Round 6
// 42.390 us; speedup vs baseline: 1.0581x; 1.0581x over previous
//
#include <hip/hip_runtime.h>
#include <hip/hip_bf16.h>

#define NB 16
#define NN 256
#define NH 8
#define ND 64
#define NT 5
#define HD (NH * ND)   // 512

typedef __bf16 bf16x8 __attribute__((ext_vector_type(8)));
typedef __bf16 bf16x4 __attribute__((ext_vector_type(4)));
typedef float  f32x4  __attribute__((ext_vector_type(4)));

__device__ __forceinline__ float4 ld4(const float* __restrict__ p) {
    return *reinterpret_cast<const float4*>(p);
}

__device__ __forceinline__ bf16x8 cvt8(float4 a, float4 b) {
    bf16x8 r;
    r[0] = (__bf16)a.x; r[1] = (__bf16)a.y; r[2] = (__bf16)a.z; r[3] = (__bf16)a.w;
    r[4] = (__bf16)b.x; r[5] = (__bf16)b.y; r[6] = (__bf16)b.z; r[7] = (__bf16)b.w;
    return r;
}

// Transpose a[(h*64+dd)*64*5 + e*5 + t] (fp32) -> wt[h][t][e][dd] (bf16).
__global__ void prep_w_kernel(const float* __restrict__ a, __bf16* __restrict__ wt) {
    int idx = blockIdx.x * 256 + threadIdx.x;
    if (idx >= NH * ND * ND * NT) return;
    int t  = idx % NT;
    int e  = (idx / NT) % ND;
    int dd = (idx / (NT * ND)) % ND;
    int h  = idx / (NT * ND * ND);
    wt[(((h * NT + t) * ND + e) * ND) + dd] = (__bf16)a[idx];
}

template <bool USE_WT>
__global__ __launch_bounds__(64, 3) void mhea_kernel(
    const float* __restrict__ src, const float* __restrict__ dst,
    const float* __restrict__ araw, const __bf16* __restrict__ wt,
    const int* __restrict__ edges, float* __restrict__ out)
{
    // Wave-private P staging (1 wave per block => NO barrier, lgkmcnt only).
    // Layout: elem = t*1024 + i*64 + (e ^ ((i&7)<<3))  (bf16 elems)
    __shared__ __bf16 Plds[NT * 16 * 64];   // 10 KB

    const int it = blockIdx.x;   // 16-row i tile
    const int h  = blockIdx.y;
    const int b  = blockIdx.z;
    const int i0 = it * 16;

    const int l  = threadIdx.x & 63;
    const int il = l & 15;
    const int kg = l >> 4;       // lane k-group 0..3

    const float* dbase = dst + (size_t)b * NN * HD + h * ND;
    const int*   erow  = edges + ((size_t)b * NN + i0 + il) * NN;
    const float* sbase = src + (size_t)(b * NN + i0 + il) * HD + h * ND;

    // ---------------- entry: issue all independent loads up front ----------------
    float4 s0 = ld4(sbase + kg * 8);
    float4 s1 = ld4(sbase + kg * 8 + 4);
    float4 s2 = ld4(sbase + 32 + kg * 8);
    float4 s3 = ld4(sbase + 32 + kg * 8 + 4);

    const float* p0 = dbase + (size_t)(0 * 16 + il) * HD + kg * 8;
    const float* p1 = dbase + (size_t)(1 * 16 + il) * HD + kg * 8;
    float4 dA0 = ld4(p0), dA1 = ld4(p0 + 4), dA2 = ld4(p0 + 32), dA3 = ld4(p0 + 36);
    float4 dB0 = ld4(p1), dB1 = ld4(p1 + 4), dB2 = ld4(p1 + 32), dB3 = ld4(p1 + 36);
    int4 eA = *reinterpret_cast<const int4*>(erow + 0 * 16 + kg * 4);
    int4 eB = *reinterpret_cast<const int4*>(erow + 1 * 16 + kg * 4);

    // ---------------- Phase 1 (swapped operands): D row=e, col=i ----------------
    // A-frag = W^T (lane: e = et*16+il, 8 consecutive dd), B-frag = src (lane: i=il).
    // D: i = il, e = et*16 + kg*4 + r  -> lane holds 4 consecutive e -> 8B LDS write.
    bf16x8 af0 = cvt8(s0, s1);
    bf16x8 af1 = cvt8(s2, s3);

    #pragma unroll
    for (int t = 0; t < NT; ++t) {
        bf16x8 w0[4], w1[4];
        #pragma unroll
        for (int et = 0; et < 4; ++et) {
            if constexpr (USE_WT) {
                const __bf16* wp = wt + (((h * NT + t) * ND + et * 16 + il) * ND) + kg * 8;
                w0[et] = *reinterpret_cast<const bf16x8*>(wp);
                w1[et] = *reinterpret_cast<const bf16x8*>(wp + 32);
            } else {
                #pragma unroll
                for (int jj = 0; jj < 8; ++jj) {
                    const int e = et * 16 + il;
                    w0[et][jj] = (__bf16)araw[((size_t)(h * ND + kg * 8 + jj) * ND + e) * NT + t];
                    w1[et][jj] = (__bf16)araw[((size_t)(h * ND + kg * 8 + jj + 32) * ND + e) * NT + t];
                }
            }
        }
        #pragma unroll
        for (int et = 0; et < 4; ++et) {
            f32x4 pacc = {0.f, 0.f, 0.f, 0.f};
            pacc = __builtin_amdgcn_mfma_f32_16x16x32_bf16(w0[et], af0, pacc, 0, 0, 0);
            pacc = __builtin_amdgcn_mfma_f32_16x16x32_bf16(w1[et], af1, pacc, 0, 0, 0);
            bf16x4 pk;
            pk[0] = (__bf16)pacc[0];
            pk[1] = (__bf16)pacc[1];
            pk[2] = (__bf16)pacc[2];
            pk[3] = (__bf16)pacc[3];
            const int elem = (et * 16 + kg * 4) ^ ((il & 7) << 3);
            *reinterpret_cast<bf16x4*>(&Plds[t * 1024 + il * 64 + elem]) = pk;
        }
    }
    // Same-wave LDS RAW: compiler inserts lgkmcnt wait; no s_barrier emitted.

    // B-frags for phase 2: lane (il,kg) reads P[t][il][ks*32+kg*8 .. +7]
    bf16x8 pa[NT][2];
    #pragma unroll
    for (int t = 0; t < NT; ++t) {
        #pragma unroll
        for (int ks = 0; ks < 2; ++ks) {
            const int elem = (ks * 32 + kg * 8) ^ ((il & 7) << 3);
            pa[t][ks] = *reinterpret_cast<const bf16x8*>(&Plds[t * 1024 + il * 64 + elem]);
        }
    }

    float* obase = out + (((size_t)(b * NH + h)) * NN + i0 + il) * NN;

    // ---------------- Phase 2: 16 j-tiles, A/B double-buffer rotation ----------------
    // Consume buffer (wait lands here; data was loaded ~2 j-tiles ago), compute,
    // then refill the SAME buffer for jt+2 (issues while the other buffer computes).
    for (int p = 0; p < 8; ++p) {
        // ---- stage A: jt = 2p ----
        {
            const bf16x8 cb0 = cvt8(dA0, dA1);
            const bf16x8 cb1 = cvt8(dA2, dA3);
            const int4 ce = eA;
            if (p < 7) {
                const float* np = dbase + (size_t)((2 * p + 2) * 16 + il) * HD + kg * 8;
                dA0 = ld4(np); dA1 = ld4(np + 4); dA2 = ld4(np + 32); dA3 = ld4(np + 36);
                eA = *reinterpret_cast<const int4*>(erow + (2 * p + 2) * 16 + kg * 4);
            }
            f32x4 acc[NT];
            #pragma unroll
            for (int t = 0; t < NT; ++t) {
                acc[t] = (f32x4){0.f, 0.f, 0.f, 0.f};
                acc[t] = __builtin_amdgcn_mfma_f32_16x16x32_bf16(cb0, pa[t][0], acc[t], 0, 0, 0);
                acc[t] = __builtin_amdgcn_mfma_f32_16x16x32_bf16(cb1, pa[t][1], acc[t], 0, 0, 0);
            }
            float4 o;
            #pragma unroll
            for (int r = 0; r < 4; ++r) {
                const int ev = (&ce.x)[r];
                float x;
                if (ev < 0) { x = -1e10f; }
                else {
                    x = (ev == 0) ? acc[0][r]
                      : (ev == 1) ? acc[1][r]
                      : (ev == 2) ? acc[2][r]
                      : (ev == 3) ? acc[3][r]
                      :             acc[4][r];
                }
                (&o.x)[r] = (x >= 0.f) ? x : 0.2f * x;
            }
            *reinterpret_cast<float4*>(obase + (2 * p) * 16 + kg * 4) = o;
        }
        // ---- stage B: jt = 2p+1 ----
        {
            const bf16x8 cb0 = cvt8(dB0, dB1);
            const bf16x8 cb1 = cvt8(dB2, dB3);
            const int4 ce = eB;
            if (p < 7) {
                const float* np = dbase + (size_t)((2 * p + 3) * 16 + il) * HD + kg * 8;
                dB0 = ld4(np); dB1 = ld4(np + 4); dB2 = ld4(np + 32); dB3 = ld4(np + 36);
                eB = *reinterpret_cast<const int4*>(erow + (2 * p + 3) * 16 + kg * 4);
            }
            f32x4 acc[NT];
            #pragma unroll
            for (int t = 0; t < NT; ++t) {
                acc[t] = (f32x4){0.f, 0.f, 0.f, 0.f};
                acc[t] = __builtin_amdgcn_mfma_f32_16x16x32_bf16(cb0, pa[t][0], acc[t], 0, 0, 0);
                acc[t] = __builtin_amdgcn_mfma_f32_16x16x32_bf16(cb1, pa[t][1], acc[t], 0, 0, 0);
            }
            float4 o;
            #pragma unroll
            for (int r = 0; r < 4; ++r) {
                const int ev = (&ce.x)[r];
                float x;
                if (ev < 0) { x = -1e10f; }
                else {
                    x = (ev == 0) ? acc[0][r]
                      : (ev == 1) ? acc[1][r]
                      : (ev == 2) ? acc[2][r]
                      : (ev == 3) ? acc[3][r]
                      :             acc[4][r];
                }
                (&o.x)[r] = (x >= 0.f) ? x : 0.2f * x;
            }
            *reinterpret_cast<float4*>(obase + (2 * p + 1) * 16 + kg * 4) = o;
        }
    }
}

extern "C" void kernel_launch(void* const* d_in, const int* in_sizes, int n_in,
                              void* d_out, int out_size, void* d_ws, size_t ws_size,
                              hipStream_t stream) {
    const float* src   = (const float*)d_in[0];
    const float* dst   = (const float*)d_in[1];
    const float* a     = (const float*)d_in[2];
    const int*   edges = (const int*)d_in[3];
    float* out = (float*)d_out;

    const size_t wt_bytes = (size_t)NH * NT * ND * ND * sizeof(__bf16);
    dim3 grid(NN / 16, NH, NB);

    if (ws_size >= wt_bytes) {
        __bf16* wt = (__bf16*)d_ws;
        const int total = NH * ND * ND * NT;
        prep_w_kernel<<<(total + 255) / 256, 256, 0, stream>>>(a, wt);
        mhea_kernel<true><<<grid, 64, 0, stream>>>(src, dst, a, wt, edges, out);
    } else {
        mhea_kernel<false><<<grid, 64, 0, stream>>>(src, dst, a, nullptr, edges, out);
    }
}